// Round 7
// baseline (4403.773 us; speedup 1.0000x reference)
//
#include <hip/hip_runtime.h>
#include <math.h>

#define SEQ 2048
#define DIM 2048
#define NH 16
#define HD 128
#define CACHEB 408
#define RECENT 204
#define PEN 0.4f
#define QK_SCALE 0.08838834764831845f  // 1/sqrt(128)
#define BIGT 0x7fffffff

typedef unsigned short u16;
typedef unsigned long long u64;
typedef __attribute__((ext_vector_type(8))) short bh8;   // 8 bf16 (4 VGPRs)
typedef __attribute__((ext_vector_type(4))) float f32x4; // MFMA acc / row chunk

__device__ __forceinline__ u16 f2bf(float x) {           // RNE f32->bf16
    unsigned u = __float_as_uint(x);
    return (u16)((u + 0x7fffu + ((u >> 16) & 1u)) >> 16);
}
__device__ __forceinline__ void splitf(float x, u16& h, u16& l) {
    h = f2bf(x);
    float hf = __uint_as_float(((unsigned)h) << 16);
    l = f2bf(x - hf);
}

// ---------------- f32 -> (hi,lo) bf16 split, 4 elems/thread ---------------
__global__ __launch_bounds__(256)
void split_kernel(const float* __restrict__ src, u16* __restrict__ dh,
                  u16* __restrict__ dl, int n4)
{
    int i = blockIdx.x * 256 + threadIdx.x;
    if (i >= n4) return;
    float4 v = ((const float4*)src)[i];
    union { u16 s[4]; unsigned long long q; } oh, ol;
    splitf(v.x, oh.s[0], ol.s[0]); splitf(v.y, oh.s[1], ol.s[1]);
    splitf(v.z, oh.s[2], ol.s[2]); splitf(v.w, oh.s[3], ol.s[3]);
    ((unsigned long long*)dh)[i] = oh.q;
    ((unsigned long long*)dl)[i] = ol.q;
}

// ---------------- split-bf16 MFMA NT GEMM (direct-from-global) ------------
// Kept for QK (K=128) and PV (TRUNCA) paths.
template<bool ASPLITF32, bool BSPLITF32, bool CAUSAL, bool TRUNCA>
__global__ __launch_bounds__(256, 2)
void mfma_nt(const void* __restrict__ Ah_, const void* __restrict__ Al_,
             const void* __restrict__ Bh_, const void* __restrict__ Bl_,
             float* __restrict__ Cp, int K, int lda, int ldb, int ldc,
             long aB, long bB, long cB, float scale)
{
    int m0 = blockIdx.y * 128, n0 = blockIdx.x * 128;
    if (CAUSAL && n0 > m0 + 127) return;

    const float* Af = (const float*)Ah_ + (size_t)blockIdx.z * aB;
    const u16*   Ah = (const u16*)Ah_   + (size_t)blockIdx.z * aB;
    const u16*   Al = (const u16*)Al_   + (size_t)blockIdx.z * aB;
    const float* Bf = (const float*)Bh_ + (size_t)blockIdx.z * bB;
    const u16*   Bh = (const u16*)Bh_   + (size_t)blockIdx.z * bB;
    const u16*   Bl = (const u16*)Bl_   + (size_t)blockIdx.z * bB;
    float* C = Cp + (size_t)blockIdx.z * cB;

    int lane = threadIdx.x & 63, wave = threadIdx.x >> 6;
    int wm = m0 + (wave >> 1) * 64, wn = n0 + (wave & 1) * 64;
    int fr = lane & 15, quad = lane >> 4;
    int kq = quad * 8;

    auto loadA = [&](int mt, int k, bh8& h, bh8& l) {
        int r = wm + mt * 16 + fr;
        if (ASPLITF32) {
            const float* p = Af + (size_t)r * lda + k + kq;
            float4 x = *(const float4*)p, y = *(const float4*)(p + 4);
            u16 hh, ll;
            splitf(x.x,hh,ll); h[0]=(short)hh; l[0]=(short)ll;
            splitf(x.y,hh,ll); h[1]=(short)hh; l[1]=(short)ll;
            splitf(x.z,hh,ll); h[2]=(short)hh; l[2]=(short)ll;
            splitf(x.w,hh,ll); h[3]=(short)hh; l[3]=(short)ll;
            splitf(y.x,hh,ll); h[4]=(short)hh; l[4]=(short)ll;
            splitf(y.y,hh,ll); h[5]=(short)hh; l[5]=(short)ll;
            splitf(y.z,hh,ll); h[6]=(short)hh; l[6]=(short)ll;
            splitf(y.w,hh,ll); h[7]=(short)hh; l[7]=(short)ll;
        } else {
            h = *(const bh8*)(Ah + (size_t)r * lda + k + kq);
            l = *(const bh8*)(Al + (size_t)r * lda + k + kq);
        }
    };
    auto loadB = [&](int nt, int k, bh8& h, bh8& l) {
        int r = wn + nt * 16 + fr;
        if (BSPLITF32) {
            const float* p = Bf + (size_t)r * ldb + k + kq;
            float4 x = *(const float4*)p, y = *(const float4*)(p + 4);
            u16 hh, ll;
            splitf(x.x,hh,ll); h[0]=(short)hh; l[0]=(short)ll;
            splitf(x.y,hh,ll); h[1]=(short)hh; l[1]=(short)ll;
            splitf(x.z,hh,ll); h[2]=(short)hh; l[2]=(short)ll;
            splitf(x.w,hh,ll); h[3]=(short)hh; l[3]=(short)ll;
            splitf(y.x,hh,ll); h[4]=(short)hh; l[4]=(short)ll;
            splitf(y.y,hh,ll); h[5]=(short)hh; l[5]=(short)ll;
            splitf(y.z,hh,ll); h[6]=(short)hh; l[6]=(short)ll;
            splitf(y.w,hh,ll); h[7]=(short)hh; l[7]=(short)ll;
        } else {
            h = *(const bh8*)(Bh + (size_t)r * ldb + k + kq);
            l = *(const bh8*)(Bl + (size_t)r * ldb + k + kq);
        }
    };

    f32x4 acc[4][4] = {};
    int Keff = TRUNCA ? min(K, m0 + 128) : K;

    for (int k0 = 0; k0 < Keff; k0 += 32) {
        bh8 ah[4], al[4], bh[4], bl[4];
        #pragma unroll
        for (int i = 0; i < 4; i++) { loadA(i, k0, ah[i], al[i]); loadB(i, k0, bh[i], bl[i]); }
        #pragma unroll
        for (int mt = 0; mt < 4; mt++)
            #pragma unroll
            for (int nt = 0; nt < 4; nt++) {
                acc[mt][nt] = __builtin_amdgcn_mfma_f32_16x16x32_bf16(ah[mt], bh[nt], acc[mt][nt], 0, 0, 0);
                acc[mt][nt] = __builtin_amdgcn_mfma_f32_16x16x32_bf16(ah[mt], bl[nt], acc[mt][nt], 0, 0, 0);
                acc[mt][nt] = __builtin_amdgcn_mfma_f32_16x16x32_bf16(al[mt], bh[nt], acc[mt][nt], 0, 0, 0);
            }
    }

    #pragma unroll
    for (int mt = 0; mt < 4; mt++)
        #pragma unroll
        for (int r = 0; r < 4; r++) {
            int row = wm + mt * 16 + quad * 4 + r;
            #pragma unroll
            for (int nt = 0; nt < 4; nt++) {
                int col = wn + nt * 16 + fr;
                C[(size_t)row * ldc + col] = acc[mt][nt][r] * scale;
            }
        }
}

// ---------------- split-bf16 MFMA NT GEMM, LDS-staged (2048^3 only) -------
__global__ __launch_bounds__(256, 2)
void gemm_nt_staged(const u16* __restrict__ Ah, const u16* __restrict__ Al,
                    const u16* __restrict__ Bh, const u16* __restrict__ Bl,
                    float* __restrict__ C, float scale)
{
    __shared__ u16 sm[2][4][128 * 32];   // [buf][Ah,Al,Bh,Bl][row*32+col], 64 KB

    int m0 = blockIdx.y * 128, n0 = blockIdx.x * 128;
    int tid = threadIdx.x;
    int lane = tid & 63, wave = tid >> 6;
    int fr = lane & 15, quad = lane >> 4;
    int wmr = (wave >> 1) * 64;
    int wnr = (wave & 1) * 64;

    auto stage = [&](int buf, int k0) {
        #pragma unroll
        for (int a = 0; a < 4; a++) {
            const u16* g = (a == 0) ? Ah : (a == 1) ? Al : (a == 2) ? Bh : Bl;
            int r0 = (a < 2) ? m0 : n0;
            #pragma unroll
            for (int hf = 0; hf < 2; hf++) {
                int c = hf * 256 + wave * 64 + lane;
                const u16* src = g + (size_t)(r0 + (c >> 2)) * DIM + k0 + (c & 3) * 8;
                u16* dst = &sm[buf][a][(hf * 256 + wave * 64) * 8];
                __builtin_amdgcn_global_load_lds(
                    (const __attribute__((address_space(1))) void*)src,
                    (__attribute__((address_space(3))) void*)dst, 16, 0, 0);
            }
        }
    };

    f32x4 acc[4][4] = {};

    auto cmpt = [&](int buf) {
        bh8 ah[4], al[4], bhf[4], blf[4];
        #pragma unroll
        for (int i = 0; i < 4; i++) {
            int ra = (wmr + i * 16 + fr) * 32 + quad * 8;
            int rb = (wnr + i * 16 + fr) * 32 + quad * 8;
            ah[i]  = *(const bh8*)&sm[buf][0][ra];
            al[i]  = *(const bh8*)&sm[buf][1][ra];
            bhf[i] = *(const bh8*)&sm[buf][2][rb];
            blf[i] = *(const bh8*)&sm[buf][3][rb];
        }
        #pragma unroll
        for (int mt = 0; mt < 4; mt++)
            #pragma unroll
            for (int nt = 0; nt < 4; nt++) {
                acc[mt][nt] = __builtin_amdgcn_mfma_f32_16x16x32_bf16(ah[mt], bhf[nt], acc[mt][nt], 0, 0, 0);
                acc[mt][nt] = __builtin_amdgcn_mfma_f32_16x16x32_bf16(ah[mt], blf[nt], acc[mt][nt], 0, 0, 0);
                acc[mt][nt] = __builtin_amdgcn_mfma_f32_16x16x32_bf16(al[mt], bhf[nt], acc[mt][nt], 0, 0, 0);
            }
    };

    stage(0, 0);
    __syncthreads();
    int cur = 0;
    for (int k0 = 0; k0 < DIM; k0 += 32) {
        if (k0 + 32 < DIM) stage(cur ^ 1, k0 + 32);
        cmpt(cur);
        __syncthreads();
        cur ^= 1;
    }

    int wm = m0 + wmr, wn = n0 + wnr;
    #pragma unroll
    for (int mt = 0; mt < 4; mt++)
        #pragma unroll
        for (int r = 0; r < 4; r++) {
            int row = wm + mt * 16 + quad * 4 + r;
            #pragma unroll
            for (int nt = 0; nt < 4; nt++) {
                int col = wn + nt * 16 + fr;
                C[(size_t)row * DIM + col] = acc[mt][nt][r] * scale;
            }
        }
}

// ---------------- RoPE in place on Q and K (f32) ---------------------------
__global__ __launch_bounds__(256)
void rope_qk(float* __restrict__ Q, float* __restrict__ K, const int* __restrict__ pos_ids)
{
    int s = blockIdx.x;
    int i = threadIdx.x & 63;
    int h = blockIdx.y * 4 + (threadIdx.x >> 6);
    double p = (double)pos_ids[s];
    double invf = exp(-((double)(2 * i) / (double)HD) * 9.210340371976184); // ln(10000)
    double ang = p * invf;
    float c = (float)cos(ang), sn = (float)sin(ang);
    size_t b = (size_t)s * DIM + (size_t)h * HD;
    float q0 = Q[b + i], q1 = Q[b + i + 64];
    Q[b + i]      = q0 * c - q1 * sn;
    Q[b + i + 64] = q1 * c + q0 * sn;
    float k0 = K[b + i], k1 = K[b + i + 64];
    K[b + i]      = k0 * c - k1 * sn;
    K[b + i + 64] = k1 * c + k0 * sn;
}

// ---------------- V(f32) -> Vt hi/lo bf16 [h][hd][s] -----------------------
__global__ __launch_bounds__(1024)
void transpose_v(const float* __restrict__ V, u16* __restrict__ Vth, u16* __restrict__ Vtl)
{
    __shared__ float tile[32][33];
    int h = blockIdx.z;
    int j0 = blockIdx.x * 32, d0 = blockIdx.y * 32;
    int tx = threadIdx.x, ty = threadIdx.y;
    tile[ty][tx] = V[(size_t)(j0 + ty) * DIM + (size_t)h * HD + d0 + tx];
    __syncthreads();
    u16 hh, ll; splitf(tile[tx][ty], hh, ll);
    size_t idx = (size_t)h * HD * SEQ + (size_t)(d0 + ty) * SEQ + j0 + tx;
    Vth[idx] = hh; Vtl[idx] = ll;
}

// ---------------- row softmax (causal) in place on Sc ---------------------
__global__ __launch_bounds__(256)
void softmax_rows(float* __restrict__ Sc)
{
    int r = blockIdx.x, h = blockIdx.y;
    float* row = Sc + ((size_t)h * SEQ + r) * SEQ;
    int n = r + 1;
    __shared__ float red[256];
    int tid = threadIdx.x;
    float mx = -INFINITY;
    for (int j = tid; j < n; j += 256) mx = fmaxf(mx, row[j]);
    red[tid] = mx; __syncthreads();
    for (int s = 128; s; s >>= 1) { if (tid < s) red[tid] = fmaxf(red[tid], red[tid + s]); __syncthreads(); }
    mx = red[0]; __syncthreads();
    float sum = 0.f;
    for (int j = tid; j < n; j += 256) { float e = expf(row[j] - mx); row[j] = e; sum += e; }
    red[tid] = sum; __syncthreads();
    for (int s = 128; s; s >>= 1) { if (tid < s) red[tid] += red[tid + s]; __syncthreads(); }
    float inv = 1.f / red[0];
    for (int j = tid; j < n; j += 256) row[j] *= inv;
    for (int j = n + tid; j < SEQ; j += 256) row[j] = 0.f;
}

// ---------------- parallel warmup: select0[h][c] = sum_t PEN^(407-t)*Sc[t][c]
__global__ __launch_bounds__(256)
void warmup_select(const float* __restrict__ Sc, float* __restrict__ sel0)
{
    int h = blockIdx.y;
    int col = blockIdx.x * 256 + threadIdx.x;
    const float* S = Sc + (size_t)h * SEQ * SEQ + col;
    float s = 0.f;
    #pragma unroll 4
    for (int t = 0; t < CACHEB; t++) s = PEN * s + S[(size_t)t * SEQ];
    sel0[h * SEQ + col] = s;
}

// ---------------- DPP cross-lane helpers ----------------------------------
#define DPP_SUMSTEP(x, ctrl) \
    x += __int_as_float(__builtin_amdgcn_update_dpp(0, __float_as_int(x), ctrl, 0xF, 0xF, true))
#define DPP_SUMBC(x, ctrl) \
    x += __int_as_float(__builtin_amdgcn_update_dpp(0, __float_as_int(x), ctrl, 0xF, 0xF, false))

__device__ __forceinline__ float wave_sum64(float x) {
    DPP_SUMSTEP(x, 0x111); DPP_SUMSTEP(x, 0x112);
    DPP_SUMSTEP(x, 0x114); DPP_SUMSTEP(x, 0x118);
    DPP_SUMBC(x, 0x142);   DPP_SUMBC(x, 0x143);
    return __int_as_float(__builtin_amdgcn_readlane(__float_as_int(x), 63));
}

// 64-bit (value,pos) key min-reduction across the wave.
#define DPP_MIN_U64(x, ctrl) do { \
    unsigned lo_ = (unsigned)(x), hi_ = (unsigned)((x) >> 32); \
    unsigned nlo_ = (unsigned)__builtin_amdgcn_update_dpp((int)lo_, (int)lo_, ctrl, 0xF, 0xF, false); \
    unsigned nhi_ = (unsigned)__builtin_amdgcn_update_dpp((int)hi_, (int)hi_, ctrl, 0xF, 0xF, false); \
    u64 o_ = ((u64)nhi_ << 32) | nlo_; \
    if (o_ < (x)) (x) = o_; \
} while (0)

__device__ __forceinline__ u64 wave_min64_u64(u64 x) {
    DPP_MIN_U64(x, 0x111); DPP_MIN_U64(x, 0x112);
    DPP_MIN_U64(x, 0x114); DPP_MIN_U64(x, 0x118);
    DPP_MIN_U64(x, 0x142); DPP_MIN_U64(x, 0x143);
    unsigned rlo = (unsigned)__builtin_amdgcn_readlane((int)(unsigned)x, 63);
    unsigned rhi = (unsigned)__builtin_amdgcn_readlane((int)(unsigned)(x >> 32), 63);
    return ((u64)rhi << 32) | rlo;
}

// sign-extend bit k of msk to all 32 bits (0 or 0xFFFFFFFF)
#define SEXT_BIT(msk, k) ((unsigned)(((int)((msk) << (31 - (k)))) >> 31))

#define RING 12   // LDS ring slots (>= prefetch depth 8 + slack vs WAR hazard)

// ---------------- H2O scan: 1 wave, LDS-ring DMA prefetch, counted vmcnt ---
// Arithmetic is the verbatim scan6 step (bit-exact). Rows are DMA'd
// global->LDS 8 deep via global_load_lds (no VGPR destinations -> no
// register-shuffle hazard), consumed behind a manual s_waitcnt vmcnt(56)
// (56 = 7 rows x 8 chunks stay in flight). The LDS row is read by ONE asm
// block bundling 8x ds_read_b128 + s_waitcnt lgkmcnt(0), so its outputs are
// ready at block end (no hazard window) and the compiler sees no LDS
// dependency to conservatively drain.
__global__ __launch_bounds__(64, 1)
void h2o_scan10(const float* __restrict__ Sc, const float* __restrict__ sel0,
                int* __restrict__ evict)
{
    __shared__ float ring[RING * SEQ];    // 96 KB
    __shared__ int et[SEQ];               // 8 KB

    int h = blockIdx.x;
    int l = threadIdx.x;                  // 0..63, one wave
    const float* Sh = Sc + (size_t)h * SEQ * SEQ;

    #pragma unroll
    for (int s = 0; s < SEQ / 64; s++) et[s * 64 + l] = BIGT;

    float sel[32];
    const float* s0 = sel0 + h * SEQ + l * 4;
    #pragma unroll
    for (int i = 0; i < 8; i++) {
        float4 v = *(const float4*)(s0 + i * 256);
        sel[i*4+0]=v.x; sel[i*4+1]=v.y; sel[i*4+2]=v.z; sel[i*4+3]=v.w;
    }

    unsigned mask = 0xffffffffu;
    unsigned candBits = 0;
    unsigned lo32[32];
    #pragma unroll
    for (int k = 0; k < 32; k++) {
        int p = ((k >> 2) << 8) + l * 4 + (k & 3);
        lo32[k] = (unsigned)p;
        if (p <= CACHEB - RECENT) candBits |= 1u << k;
    }

    // DMA one row (8 KB) into ring slot: per-lane global src, wave-uniform
    // LDS dst (global_load_lds writes lane i at dst + i*16).
    auto dma_row = [&](int r, int slot) {
        const float* src = Sh + (size_t)r * SEQ + l * 4;
        float* dst0 = &ring[slot * SEQ];
        #pragma unroll
        for (int i = 0; i < 8; i++) {
            __builtin_amdgcn_global_load_lds(
                (const __attribute__((address_space(1))) void*)(src + i * 256),
                (__attribute__((address_space(3))) void*)(dst0 + i * 256), 16, 0, 0);
        }
    };

    unsigned ringbase =
        (unsigned)(unsigned long long)(__attribute__((address_space(3))) float*)ring;

    // read a full row from LDS: one asm block, 8x ds_read_b128 + lgkmcnt(0);
    // outputs are complete when the block retires.
    auto lds_read = [&](int slot, f32x4 (&b)[8]) {
        unsigned addr = ringbase + (unsigned)(slot * SEQ * 4) + (unsigned)(l * 16);
        asm volatile(
            "ds_read_b128 %0, %8 offset:0\n\t"
            "ds_read_b128 %1, %8 offset:1024\n\t"
            "ds_read_b128 %2, %8 offset:2048\n\t"
            "ds_read_b128 %3, %8 offset:3072\n\t"
            "ds_read_b128 %4, %8 offset:4096\n\t"
            "ds_read_b128 %5, %8 offset:5120\n\t"
            "ds_read_b128 %6, %8 offset:6144\n\t"
            "ds_read_b128 %7, %8 offset:7168\n\t"
            "s_waitcnt lgkmcnt(0)"
            : "=&v"(b[0]), "=&v"(b[1]), "=&v"(b[2]), "=&v"(b[3]),
              "=&v"(b[4]), "=&v"(b[5]), "=&v"(b[6]), "=&v"(b[7])
            : "v"(addr)
            : "memory");
    };

    auto step = [&](int t, f32x4 (&cur)[8]) {
        float m[32];
        float p0 = 0.f, p1 = 0.f, p2 = 0.f, p3 = 0.f;
        #pragma unroll
        for (int i = 0; i < 8; i++) {
            f32x4 b = cur[i];
            m[i*4+0] = __uint_as_float(__float_as_uint(b[0]) & SEXT_BIT(mask, i*4+0));
            m[i*4+1] = __uint_as_float(__float_as_uint(b[1]) & SEXT_BIT(mask, i*4+1));
            m[i*4+2] = __uint_as_float(__float_as_uint(b[2]) & SEXT_BIT(mask, i*4+2));
            m[i*4+3] = __uint_as_float(__float_as_uint(b[3]) & SEXT_BIT(mask, i*4+3));
            p0 += m[i*4+0]; p1 += m[i*4+1]; p2 += m[i*4+2]; p3 += m[i*4+3];
        }
        #pragma unroll
        for (int k = 0; k < 32; k++) sel[k] *= PEN;
        float part = wave_sum64((p0 + p1) + (p2 + p3));
        float inv = 1.f / part;

        unsigned ncm = ~(mask & candBits);
        u64 t16[16];
        #pragma unroll
        for (int k = 0; k < 16; k++) {
            float sa = fmaf(m[k],      inv, sel[k]);      sel[k]      = sa;
            float sb = fmaf(m[k + 16], inv, sel[k + 16]); sel[k + 16] = sb;
            unsigned ha = __float_as_uint(sa) | SEXT_BIT(ncm, k);
            unsigned hb = __float_as_uint(sb) | SEXT_BIT(ncm, k + 16);
            u64 ka = ((u64)ha << 32) | lo32[k];
            u64 kb = ((u64)hb << 32) | lo32[k + 16];
            t16[k] = ka < kb ? ka : kb;
        }
        u64 t8[8];
        #pragma unroll
        for (int k = 0; k < 8; k++) t8[k] = t16[k] < t16[k + 8] ? t16[k] : t16[k + 8];
        u64 t4[4];
        #pragma unroll
        for (int k = 0; k < 4; k++) t4[k] = t8[k] < t8[k + 4] ? t8[k] : t8[k + 4];
        u64 t2a = t4[0] < t4[1] ? t4[0] : t4[1];
        u64 t2b = t4[2] < t4[3] ? t4[2] : t4[3];
        u64 lmin = t2a < t2b ? t2a : t2b;
        u64 g = wave_min64_u64(lmin);

        unsigned bpos = (unsigned)g & 0x7ffu;
        int ke = (((int)(bpos >> 8)) << 2) | (int)(bpos & 3);
        if ((((int)bpos >> 2) & 63) == l) mask &= ~(1u << ke);
        if (l == 0) et[bpos] = t;

        int newc = t + 1 - RECENT;
        if (((newc >> 2) & 63) == l) candBits |= 1u << (((newc >> 8) << 2) | (newc & 3));
    };

    // prologue: stage rows CACHEB..CACHEB+7 (slots 0..7; 408 % 12 == 0)
    #pragma unroll
    for (int i = 0; i < 8; i++) dma_row(CACHEB + i, i);

    int rs = 0;        // slot of row t
    int is = 8;        // slot of row t+8
    for (int t = CACHEB; t <= SEQ - 9; ++t) {          // t+8 <= 2047
        asm volatile("s_waitcnt vmcnt(56)" ::: "memory");
        __builtin_amdgcn_sched_barrier(0);
        f32x4 cur[8];
        lds_read(rs, cur);
        dma_row(t + 8, is);                            // keep 8 rows in flight
        step(t, cur);
        rs = (rs == RING - 1) ? 0 : rs + 1;
        is = (is == RING - 1) ? 0 : is + 1;
    }
    asm volatile("s_waitcnt vmcnt(0)" ::: "memory");
    __builtin_amdgcn_sched_barrier(0);
    for (int t = SEQ - 8; t <= SEQ - 2; ++t) {         // 2040..2046
        f32x4 cur[8];
        lds_read(rs, cur);
        step(t, cur);
        rs = (rs == RING - 1) ? 0 : rs + 1;
    }

    #pragma unroll
    for (int s = 0; s < SEQ / 64; s++)
        evict[h * SEQ + s * 64 + l] = et[s * 64 + l];
}

// ---------------- apply mask + renormalize rows >= CACHEB in place --------
__global__ __launch_bounds__(256)
void mask_renorm(float* __restrict__ Sc, const int* __restrict__ evict)
{
    int r = CACHEB + blockIdx.x;
    int h = blockIdx.y;
    float* row = Sc + ((size_t)h * SEQ + r) * SEQ;
    const int* et = evict + h * SEQ;
    int tid = threadIdx.x;
    __shared__ float red[256];
    float v[8]; float sum = 0.f;
    #pragma unroll
    for (int s = 0; s < 8; s++) {
        int c = s * 256 + tid;
        float x = row[c];
        v[s] = (et[c] >= r) ? x : 0.f;
        sum += v[s];
    }
    red[tid] = sum; __syncthreads();
    for (int s = 128; s; s >>= 1) { if (tid < s) red[tid] += red[tid + s]; __syncthreads(); }
    float inv = 1.f / red[0];
    #pragma unroll
    for (int s = 0; s < 8; s++) row[s * 256 + tid] = v[s] * inv;
}

extern "C" void kernel_launch(void* const* d_in, const int* in_sizes, int n_in,
                              void* d_out, int out_size, void* d_ws, size_t ws_size,
                              hipStream_t stream)
{
    const float* hidden = (const float*)d_in[0];
    const int*   pos    = (const int*)d_in[2];
    const float* wq     = (const float*)d_in[3];
    const float* wk     = (const float*)d_in[4];
    const float* wv     = (const float*)d_in[5];
    const float* wo     = (const float*)d_in[6];
    float* out = (float*)d_out;

    float* ws = (float*)d_ws;
    const size_t SD = (size_t)SEQ * DIM;           // 4M elems
    float* Q    = ws;                              // f32, 16 MB
    float* K    = ws + SD;                         // f32, 16 MB
    float* V    = ws + 2 * SD;                     // f32; becomes O after transpose
    float* O    = V;
    u16*   Vth  = (u16*)(ws + 3 * SD);             // bf16-hi Vt (8 MB)
    u16*   Vtl  = Vth + SD;                        // bf16-lo Vt (8 MB)
    float* sel0 = ws + 4 * SD;                     // NH*SEQ floats
    int*   evct = (int*)(ws + 4 * SD + (size_t)NH * SEQ);
    float* Sc   = ws + 4 * SD + 2 * (size_t)NH * SEQ;   // g * SEQ*SEQ floats

    // staging (hi/lo splits) in the not-yet-used Sc region: 4 arrays x SD u16
    u16* hh = (u16*)Sc;        // hidden hi (later: O hi)
    u16* hl = hh + SD;         // hidden lo (later: O lo)
    u16* wh = hl + SD;         // current weight hi (reused per weight)
    u16* wl = wh + SD;         // current weight lo

    const size_t fixedB   = (4 * SD + 2 * (size_t)NH * SEQ) * sizeof(float);
    const size_t perHeadB = (size_t)SEQ * SEQ * sizeof(float);
    int g = NH;
    while (g > 1 && fixedB + (size_t)g * perHeadB > ws_size) g >>= 1;

    const int N4 = (int)(SD / 4);
    const int CB = (N4 + 255) / 256;

    // 0-1. split + projections (weights staged sequentially), LDS-staged GEMM
    split_kernel<<<CB, 256, 0, stream>>>(hidden, hh, hl, N4);
    split_kernel<<<CB, 256, 0, stream>>>(wq, wh, wl, N4);
    gemm_nt_staged<<<dim3(16,16), 256, 0, stream>>>(hh, hl, wh, wl, Q, 1.f);
    split_kernel<<<CB, 256, 0, stream>>>(wk, wh, wl, N4);
    gemm_nt_staged<<<dim3(16,16), 256, 0, stream>>>(hh, hl, wh, wl, K, 1.f);
    split_kernel<<<CB, 256, 0, stream>>>(wv, wh, wl, N4);
    gemm_nt_staged<<<dim3(16,16), 256, 0, stream>>>(hh, hl, wh, wl, V, 1.f);

    // 2. RoPE on Q, K (f32, in place)
    rope_qk<<<dim3(SEQ, NH / 4), 256, 0, stream>>>(Q, K, pos);

    // 3. V -> Vt hi/lo (V storage then becomes O)
    transpose_v<<<dim3(SEQ / 32, HD / 32, NH), dim3(32, 32), 0, stream>>>(V, Vth, Vtl);

    // 4-8 per head-group
    for (int h0 = 0; h0 < NH; h0 += g) {
        int gc = min(g, NH - h0);
        // QK logits: f32 Q,K split in-register, causal tiles, f32 out
        mfma_nt<true,true,true,false><<<dim3(16,16,gc), 256, 0, stream>>>(
            Q + (size_t)h0 * HD, nullptr, K + (size_t)h0 * HD, nullptr, Sc, HD,
            DIM, DIM, SEQ, HD, HD, (long)SEQ * SEQ, QK_SCALE);
        softmax_rows<<<dim3(SEQ, gc), 256, 0, stream>>>(Sc);
        warmup_select<<<dim3(SEQ / 256, gc), 256, 0, stream>>>(Sc, sel0);
        h2o_scan10<<<dim3(gc), 64, 0, stream>>>(Sc, sel0, evct);
        mask_renorm<<<dim3(SEQ - CACHEB, gc), 256, 0, stream>>>(Sc, evct);
        // PV: probs f32 split in-register (K-truncated), Vt pre-split, f32 out
        mfma_nt<true,false,false,true><<<dim3(1,16,gc), 256, 0, stream>>>(
            Sc, nullptr, Vth + (size_t)h0 * HD * SEQ, Vtl + (size_t)h0 * HD * SEQ,
            O + (size_t)h0 * HD, SEQ, SEQ, SEQ, DIM,
            (long)SEQ * SEQ, (long)HD * SEQ, HD, 1.f);
    }

    // 9. final projection via staged path: pre-split O, then out = O @ wo^T.
    split_kernel<<<CB, 256, 0, stream>>>(O, hh, hl, N4);
    split_kernel<<<CB, 256, 0, stream>>>(wo, wh, wl, N4);
    gemm_nt_staged<<<dim3(16,16), 256, 0, stream>>>(hh, hl, wh, wl, out, 1.f);
}

// Round 8
// 3617.632 us; speedup vs baseline: 1.2173x; 1.2173x over previous
//
#include <hip/hip_runtime.h>
#include <math.h>

#define SEQ 2048
#define DIM 2048
#define NH 16
#define HD 128
#define CACHEB 408
#define RECENT 204
#define PEN 0.4f
#define QK_SCALE 0.08838834764831845f  // 1/sqrt(128)
#define BIGT 0x7fffffff

typedef unsigned short u16;
typedef unsigned long long u64;
typedef __attribute__((ext_vector_type(8))) short bh8;   // 8 bf16 (4 VGPRs)
typedef __attribute__((ext_vector_type(4))) float f32x4; // MFMA acc

__device__ __forceinline__ u16 f2bf(float x) {           // RNE f32->bf16
    unsigned u = __float_as_uint(x);
    return (u16)((u + 0x7fffu + ((u >> 16) & 1u)) >> 16);
}
__device__ __forceinline__ void splitf(float x, u16& h, u16& l) {
    h = f2bf(x);
    float hf = __uint_as_float(((unsigned)h) << 16);
    l = f2bf(x - hf);
}

// ---------------- f32 -> (hi,lo) bf16 split, 4 elems/thread ---------------
__global__ __launch_bounds__(256)
void split_kernel(const float* __restrict__ src, u16* __restrict__ dh,
                  u16* __restrict__ dl, int n4)
{
    int i = blockIdx.x * 256 + threadIdx.x;
    if (i >= n4) return;
    float4 v = ((const float4*)src)[i];
    union { u16 s[4]; unsigned long long q; } oh, ol;
    splitf(v.x, oh.s[0], ol.s[0]); splitf(v.y, oh.s[1], ol.s[1]);
    splitf(v.z, oh.s[2], ol.s[2]); splitf(v.w, oh.s[3], ol.s[3]);
    ((unsigned long long*)dh)[i] = oh.q;
    ((unsigned long long*)dl)[i] = ol.q;
}

// ---------------- split-bf16 MFMA NT GEMM (direct-from-global) ------------
// Kept for QK (K=128) and PV (TRUNCA) paths.
template<bool ASPLITF32, bool BSPLITF32, bool CAUSAL, bool TRUNCA>
__global__ __launch_bounds__(256, 2)
void mfma_nt(const void* __restrict__ Ah_, const void* __restrict__ Al_,
             const void* __restrict__ Bh_, const void* __restrict__ Bl_,
             float* __restrict__ Cp, int K, int lda, int ldb, int ldc,
             long aB, long bB, long cB, float scale)
{
    int m0 = blockIdx.y * 128, n0 = blockIdx.x * 128;
    if (CAUSAL && n0 > m0 + 127) return;

    const float* Af = (const float*)Ah_ + (size_t)blockIdx.z * aB;
    const u16*   Ah = (const u16*)Ah_   + (size_t)blockIdx.z * aB;
    const u16*   Al = (const u16*)Al_   + (size_t)blockIdx.z * aB;
    const float* Bf = (const float*)Bh_ + (size_t)blockIdx.z * bB;
    const u16*   Bh = (const u16*)Bh_   + (size_t)blockIdx.z * bB;
    const u16*   Bl = (const u16*)Bl_   + (size_t)blockIdx.z * bB;
    float* C = Cp + (size_t)blockIdx.z * cB;

    int lane = threadIdx.x & 63, wave = threadIdx.x >> 6;
    int wm = m0 + (wave >> 1) * 64, wn = n0 + (wave & 1) * 64;
    int fr = lane & 15, quad = lane >> 4;
    int kq = quad * 8;

    auto loadA = [&](int mt, int k, bh8& h, bh8& l) {
        int r = wm + mt * 16 + fr;
        if (ASPLITF32) {
            const float* p = Af + (size_t)r * lda + k + kq;
            float4 x = *(const float4*)p, y = *(const float4*)(p + 4);
            u16 hh, ll;
            splitf(x.x,hh,ll); h[0]=(short)hh; l[0]=(short)ll;
            splitf(x.y,hh,ll); h[1]=(short)hh; l[1]=(short)ll;
            splitf(x.z,hh,ll); h[2]=(short)hh; l[2]=(short)ll;
            splitf(x.w,hh,ll); h[3]=(short)hh; l[3]=(short)ll;
            splitf(y.x,hh,ll); h[4]=(short)hh; l[4]=(short)ll;
            splitf(y.y,hh,ll); h[5]=(short)hh; l[5]=(short)ll;
            splitf(y.z,hh,ll); h[6]=(short)hh; l[6]=(short)ll;
            splitf(y.w,hh,ll); h[7]=(short)hh; l[7]=(short)ll;
        } else {
            h = *(const bh8*)(Ah + (size_t)r * lda + k + kq);
            l = *(const bh8*)(Al + (size_t)r * lda + k + kq);
        }
    };
    auto loadB = [&](int nt, int k, bh8& h, bh8& l) {
        int r = wn + nt * 16 + fr;
        if (BSPLITF32) {
            const float* p = Bf + (size_t)r * ldb + k + kq;
            float4 x = *(const float4*)p, y = *(const float4*)(p + 4);
            u16 hh, ll;
            splitf(x.x,hh,ll); h[0]=(short)hh; l[0]=(short)ll;
            splitf(x.y,hh,ll); h[1]=(short)hh; l[1]=(short)ll;
            splitf(x.z,hh,ll); h[2]=(short)hh; l[2]=(short)ll;
            splitf(x.w,hh,ll); h[3]=(short)hh; l[3]=(short)ll;
            splitf(y.x,hh,ll); h[4]=(short)hh; l[4]=(short)ll;
            splitf(y.y,hh,ll); h[5]=(short)hh; l[5]=(short)ll;
            splitf(y.z,hh,ll); h[6]=(short)hh; l[6]=(short)ll;
            splitf(y.w,hh,ll); h[7]=(short)hh; l[7]=(short)ll;
        } else {
            h = *(const bh8*)(Bh + (size_t)r * ldb + k + kq);
            l = *(const bh8*)(Bl + (size_t)r * ldb + k + kq);
        }
    };

    f32x4 acc[4][4] = {};
    int Keff = TRUNCA ? min(K, m0 + 128) : K;

    for (int k0 = 0; k0 < Keff; k0 += 32) {
        bh8 ah[4], al[4], bh[4], bl[4];
        #pragma unroll
        for (int i = 0; i < 4; i++) { loadA(i, k0, ah[i], al[i]); loadB(i, k0, bh[i], bl[i]); }
        #pragma unroll
        for (int mt = 0; mt < 4; mt++)
            #pragma unroll
            for (int nt = 0; nt < 4; nt++) {
                acc[mt][nt] = __builtin_amdgcn_mfma_f32_16x16x32_bf16(ah[mt], bh[nt], acc[mt][nt], 0, 0, 0);
                acc[mt][nt] = __builtin_amdgcn_mfma_f32_16x16x32_bf16(ah[mt], bl[nt], acc[mt][nt], 0, 0, 0);
                acc[mt][nt] = __builtin_amdgcn_mfma_f32_16x16x32_bf16(al[mt], bh[nt], acc[mt][nt], 0, 0, 0);
            }
    }

    #pragma unroll
    for (int mt = 0; mt < 4; mt++)
        #pragma unroll
        for (int r = 0; r < 4; r++) {
            int row = wm + mt * 16 + quad * 4 + r;
            #pragma unroll
            for (int nt = 0; nt < 4; nt++) {
                int col = wn + nt * 16 + fr;
                C[(size_t)row * ldc + col] = acc[mt][nt][r] * scale;
            }
        }
}

// ---------------- split-bf16 MFMA NT GEMM, LDS-staged (2048^3 only) -------
__global__ __launch_bounds__(256, 2)
void gemm_nt_staged(const u16* __restrict__ Ah, const u16* __restrict__ Al,
                    const u16* __restrict__ Bh, const u16* __restrict__ Bl,
                    float* __restrict__ C, float scale)
{
    __shared__ u16 sm[2][4][128 * 32];   // [buf][Ah,Al,Bh,Bl][row*32+col], 64 KB

    int m0 = blockIdx.y * 128, n0 = blockIdx.x * 128;
    int tid = threadIdx.x;
    int lane = tid & 63, wave = tid >> 6;
    int fr = lane & 15, quad = lane >> 4;
    int wmr = (wave >> 1) * 64;
    int wnr = (wave & 1) * 64;

    auto stage = [&](int buf, int k0) {
        #pragma unroll
        for (int a = 0; a < 4; a++) {
            const u16* g = (a == 0) ? Ah : (a == 1) ? Al : (a == 2) ? Bh : Bl;
            int r0 = (a < 2) ? m0 : n0;
            #pragma unroll
            for (int hf = 0; hf < 2; hf++) {
                int c = hf * 256 + wave * 64 + lane;
                const u16* src = g + (size_t)(r0 + (c >> 2)) * DIM + k0 + (c & 3) * 8;
                u16* dst = &sm[buf][a][(hf * 256 + wave * 64) * 8];
                __builtin_amdgcn_global_load_lds(
                    (const __attribute__((address_space(1))) void*)src,
                    (__attribute__((address_space(3))) void*)dst, 16, 0, 0);
            }
        }
    };

    f32x4 acc[4][4] = {};

    auto cmpt = [&](int buf) {
        bh8 ah[4], al[4], bhf[4], blf[4];
        #pragma unroll
        for (int i = 0; i < 4; i++) {
            int ra = (wmr + i * 16 + fr) * 32 + quad * 8;
            int rb = (wnr + i * 16 + fr) * 32 + quad * 8;
            ah[i]  = *(const bh8*)&sm[buf][0][ra];
            al[i]  = *(const bh8*)&sm[buf][1][ra];
            bhf[i] = *(const bh8*)&sm[buf][2][rb];
            blf[i] = *(const bh8*)&sm[buf][3][rb];
        }
        #pragma unroll
        for (int mt = 0; mt < 4; mt++)
            #pragma unroll
            for (int nt = 0; nt < 4; nt++) {
                acc[mt][nt] = __builtin_amdgcn_mfma_f32_16x16x32_bf16(ah[mt], bhf[nt], acc[mt][nt], 0, 0, 0);
                acc[mt][nt] = __builtin_amdgcn_mfma_f32_16x16x32_bf16(ah[mt], blf[nt], acc[mt][nt], 0, 0, 0);
                acc[mt][nt] = __builtin_amdgcn_mfma_f32_16x16x32_bf16(al[mt], bhf[nt], acc[mt][nt], 0, 0, 0);
            }
    };

    stage(0, 0);
    __syncthreads();
    int cur = 0;
    for (int k0 = 0; k0 < DIM; k0 += 32) {
        if (k0 + 32 < DIM) stage(cur ^ 1, k0 + 32);
        cmpt(cur);
        __syncthreads();
        cur ^= 1;
    }

    int wm = m0 + wmr, wn = n0 + wnr;
    #pragma unroll
    for (int mt = 0; mt < 4; mt++)
        #pragma unroll
        for (int r = 0; r < 4; r++) {
            int row = wm + mt * 16 + quad * 4 + r;
            #pragma unroll
            for (int nt = 0; nt < 4; nt++) {
                int col = wn + nt * 16 + fr;
                C[(size_t)row * DIM + col] = acc[mt][nt][r] * scale;
            }
        }
}

// ---------------- RoPE in place on Q and K (f32) ---------------------------
__global__ __launch_bounds__(256)
void rope_qk(float* __restrict__ Q, float* __restrict__ K, const int* __restrict__ pos_ids)
{
    int s = blockIdx.x;
    int i = threadIdx.x & 63;
    int h = blockIdx.y * 4 + (threadIdx.x >> 6);
    double p = (double)pos_ids[s];
    double invf = exp(-((double)(2 * i) / (double)HD) * 9.210340371976184); // ln(10000)
    double ang = p * invf;
    float c = (float)cos(ang), sn = (float)sin(ang);
    size_t b = (size_t)s * DIM + (size_t)h * HD;
    float q0 = Q[b + i], q1 = Q[b + i + 64];
    Q[b + i]      = q0 * c - q1 * sn;
    Q[b + i + 64] = q1 * c + q0 * sn;
    float k0 = K[b + i], k1 = K[b + i + 64];
    K[b + i]      = k0 * c - k1 * sn;
    K[b + i + 64] = k1 * c + k0 * sn;
}

// ---------------- V(f32) -> Vt hi/lo bf16 [h][hd][s] -----------------------
__global__ __launch_bounds__(1024)
void transpose_v(const float* __restrict__ V, u16* __restrict__ Vth, u16* __restrict__ Vtl)
{
    __shared__ float tile[32][33];
    int h = blockIdx.z;
    int j0 = blockIdx.x * 32, d0 = blockIdx.y * 32;
    int tx = threadIdx.x, ty = threadIdx.y;
    tile[ty][tx] = V[(size_t)(j0 + ty) * DIM + (size_t)h * HD + d0 + tx];
    __syncthreads();
    u16 hh, ll; splitf(tile[tx][ty], hh, ll);
    size_t idx = (size_t)h * HD * SEQ + (size_t)(d0 + ty) * SEQ + j0 + tx;
    Vth[idx] = hh; Vtl[idx] = ll;
}

// ---------------- row softmax (causal) in place on Sc ---------------------
__global__ __launch_bounds__(256)
void softmax_rows(float* __restrict__ Sc)
{
    int r = blockIdx.x, h = blockIdx.y;
    float* row = Sc + ((size_t)h * SEQ + r) * SEQ;
    int n = r + 1;
    __shared__ float red[256];
    int tid = threadIdx.x;
    float mx = -INFINITY;
    for (int j = tid; j < n; j += 256) mx = fmaxf(mx, row[j]);
    red[tid] = mx; __syncthreads();
    for (int s = 128; s; s >>= 1) { if (tid < s) red[tid] = fmaxf(red[tid], red[tid + s]); __syncthreads(); }
    mx = red[0]; __syncthreads();
    float sum = 0.f;
    for (int j = tid; j < n; j += 256) { float e = expf(row[j] - mx); row[j] = e; sum += e; }
    red[tid] = sum; __syncthreads();
    for (int s = 128; s; s >>= 1) { if (tid < s) red[tid] += red[tid + s]; __syncthreads(); }
    float inv = 1.f / red[0];
    for (int j = tid; j < n; j += 256) row[j] *= inv;
    for (int j = n + tid; j < SEQ; j += 256) row[j] = 0.f;
}

// ---------------- parallel warmup: select0[h][c] = sum_t PEN^(407-t)*Sc[t][c]
__global__ __launch_bounds__(256)
void warmup_select(const float* __restrict__ Sc, float* __restrict__ sel0)
{
    int h = blockIdx.y;
    int col = blockIdx.x * 256 + threadIdx.x;
    const float* S = Sc + (size_t)h * SEQ * SEQ + col;
    float s = 0.f;
    #pragma unroll 4
    for (int t = 0; t < CACHEB; t++) s = PEN * s + S[(size_t)t * SEQ];
    sel0[h * SEQ + col] = s;
}

// ---------------- DPP cross-lane helpers ----------------------------------
#define DPP_SUMSTEP(x, ctrl) \
    x += __int_as_float(__builtin_amdgcn_update_dpp(0, __float_as_int(x), ctrl, 0xF, 0xF, true))
#define DPP_SUMBC(x, ctrl) \
    x += __int_as_float(__builtin_amdgcn_update_dpp(0, __float_as_int(x), ctrl, 0xF, 0xF, false))

__device__ __forceinline__ float wave_sum64(float x) {
    DPP_SUMSTEP(x, 0x111); DPP_SUMSTEP(x, 0x112);
    DPP_SUMSTEP(x, 0x114); DPP_SUMSTEP(x, 0x118);
    DPP_SUMBC(x, 0x142);   DPP_SUMBC(x, 0x143);
    return __int_as_float(__builtin_amdgcn_readlane(__float_as_int(x), 63));
}

// 64-bit (value,pos) key min-reduction across the wave.
#define DPP_MIN_U64(x, ctrl) do { \
    unsigned lo_ = (unsigned)(x), hi_ = (unsigned)((x) >> 32); \
    unsigned nlo_ = (unsigned)__builtin_amdgcn_update_dpp((int)lo_, (int)lo_, ctrl, 0xF, 0xF, false); \
    unsigned nhi_ = (unsigned)__builtin_amdgcn_update_dpp((int)hi_, (int)hi_, ctrl, 0xF, 0xF, false); \
    u64 o_ = ((u64)nhi_ << 32) | nlo_; \
    if (o_ < (x)) (x) = o_; \
} while (0)

__device__ __forceinline__ u64 wave_min64_u64(u64 x) {
    DPP_MIN_U64(x, 0x111); DPP_MIN_U64(x, 0x112);
    DPP_MIN_U64(x, 0x114); DPP_MIN_U64(x, 0x118);
    DPP_MIN_U64(x, 0x142); DPP_MIN_U64(x, 0x143);
    unsigned rlo = (unsigned)__builtin_amdgcn_readlane((int)(unsigned)x, 63);
    unsigned rhi = (unsigned)__builtin_amdgcn_readlane((int)(unsigned)(x >> 32), 63);
    return ((u64)rhi << 32) | rlo;
}

__device__ __forceinline__ u64 umin64(u64 a, u64 b) { return a < b ? a : b; }

// ---------------- H2O scan: slot-compacted (512 slots, 8/lane) ------------
// Exactly CACHEB+1 = 409 positions are alive at any step (1 evicted + 1
// inserted per step), so the dense 2048-column pass is 4x wasted work. Each
// slot holds (pos, sel, tie-key-low). Per step: gather 8 row values at slot
// positions (prefetched 1 step ahead -- positions for row t+1 are final at
// the end of step t), 8-wide sum + DPP, 8 sel updates (bit-identical ops:
// fmaf(m, 1.f/part, sel*PEN)), u64 keys (value | noncand-mask, pos, gid) and
// an exact integer min => identical argmin semantics ((value,pos) tie-break;
// gid only splits dummy ties). Dummy slots use pos = 2047: row[t][2047] == 0
// for all t <= 2046 (softmax zeroed) => contribute 0 to the sum, never
// candidates, sel stays 0 -- no gating logic at all. NOTE: the `part` SUM
// ORDER differs from the dense version (slot order); per-element values and
// the argmin are exact given part.
__global__ __launch_bounds__(64, 1)
void h2o_scan11(const float* __restrict__ Sc, const float* __restrict__ sel0,
                int* __restrict__ evict)
{
    __shared__ int et[SEQ];               // 8 KB

    int h = blockIdx.x;
    int l = threadIdx.x;                  // 0..63, one wave
    const float* Sh = Sc + (size_t)h * SEQ * SEQ;

    #pragma unroll
    for (int s = 0; s < SEQ / 64; s++) et[s * 64 + l] = BIGT;

    // slot state (all indexing compile-time constant -> stays in VGPRs)
    unsigned pos[8]; unsigned lowb[8]; float sel[8];
    #pragma unroll
    for (int j = 0; j < 8; j++) {
        int gid = l * 8 + j;
        int p = (gid <= CACHEB) ? gid : 2047;       // real: 0..408; dummy: 2047
        pos[j]  = (unsigned)p;
        lowb[j] = ((unsigned)p << 9) | (unsigned)gid;
        sel[j]  = sel0[h * SEQ + p];                // sel0[2047] == 0
    }

    float bA[8], bB[8];
    auto gather = [&](int t, float (&b)[8]) {
        const float* rp = Sh + (size_t)t * SEQ;
        #pragma unroll
        for (int j = 0; j < 8; j++) b[j] = rp[pos[j]];
    };
    gather(CACHEB, bA);

    auto step = [&](int t, float (&cur)[8], float (&nxt)[8], bool last) {
        // masked-row sum: alive set == slot set; dummies contribute exact 0
        float s01 = cur[0] + cur[1], s23 = cur[2] + cur[3];
        float s45 = cur[4] + cur[5], s67 = cur[6] + cur[7];
        float part = wave_sum64((s01 + s23) + (s45 + s67));
        float inv = 1.f / part;

        int tmr = t - RECENT;
        u64 k[8];
        #pragma unroll
        for (int j = 0; j < 8; j++) {
            float s2 = fmaf(cur[j], inv, sel[j] * PEN);   // identical ops to dense
            sel[j] = s2;
            // candidate iff pos <= t-RECENT; else force hi = 0xFFFFFFFF
            unsigned hi = __float_as_uint(s2) |
                          (unsigned)((int)(tmr - (int)pos[j]) >> 31);
            k[j] = ((u64)hi << 32) | lowb[j];
        }
        u64 m01 = umin64(k[0], k[1]), m23 = umin64(k[2], k[3]);
        u64 m45 = umin64(k[4], k[5]), m67 = umin64(k[6], k[7]);
        u64 lmin = umin64(umin64(m01, m23), umin64(m45, m67));
        u64 g = wave_min64_u64(lmin);

        unsigned lo32 = (unsigned)g;
        unsigned bpos = (lo32 >> 9) & 0x7ffu;
        unsigned gid  = lo32 & 0x1ffu;
        if (l == 0) et[bpos] = t;

        // insert position t+1 into the freed slot (manually unrolled: all
        // register accesses stay compile-time indexed)
        bool mine = (int)(gid >> 3) == l;
        unsigned np = (unsigned)(t + 1);
        #pragma unroll
        for (int j = 0; j < 8; j++) {
            bool hit = mine && ((gid & 7u) == (unsigned)j);
            if (hit) { pos[j] = np; lowb[j] = (np << 9) | gid; sel[j] = 0.f; }
        }

        if (!last) gather(t + 1, nxt);   // positions final; ~1 step of latency cover
    };

    int t = CACHEB;
    for (; t + 1 <= SEQ - 2; t += 2) {
        step(t,     bA, bB, false);
        step(t + 1, bB, bA, false);
    }
    if (t <= SEQ - 2) step(t, bA, bB, true);   // t = 2046

    #pragma unroll
    for (int s = 0; s < SEQ / 64; s++)
        evict[h * SEQ + s * 64 + l] = et[s * 64 + l];
}

// ---------------- apply mask + renormalize rows >= CACHEB in place --------
__global__ __launch_bounds__(256)
void mask_renorm(float* __restrict__ Sc, const int* __restrict__ evict)
{
    int r = CACHEB + blockIdx.x;
    int h = blockIdx.y;
    float* row = Sc + ((size_t)h * SEQ + r) * SEQ;
    const int* et = evict + h * SEQ;
    int tid = threadIdx.x;
    __shared__ float red[256];
    float v[8]; float sum = 0.f;
    #pragma unroll
    for (int s = 0; s < 8; s++) {
        int c = s * 256 + tid;
        float x = row[c];
        v[s] = (et[c] >= r) ? x : 0.f;
        sum += v[s];
    }
    red[tid] = sum; __syncthreads();
    for (int s = 128; s; s >>= 1) { if (tid < s) red[tid] += red[tid + s]; __syncthreads(); }
    float inv = 1.f / red[0];
    #pragma unroll
    for (int s = 0; s < 8; s++) row[s * 256 + tid] = v[s] * inv;
}

extern "C" void kernel_launch(void* const* d_in, const int* in_sizes, int n_in,
                              void* d_out, int out_size, void* d_ws, size_t ws_size,
                              hipStream_t stream)
{
    const float* hidden = (const float*)d_in[0];
    const int*   pos    = (const int*)d_in[2];
    const float* wq     = (const float*)d_in[3];
    const float* wk     = (const float*)d_in[4];
    const float* wv     = (const float*)d_in[5];
    const float* wo     = (const float*)d_in[6];
    float* out = (float*)d_out;

    float* ws = (float*)d_ws;
    const size_t SD = (size_t)SEQ * DIM;           // 4M elems
    float* Q    = ws;                              // f32, 16 MB
    float* K    = ws + SD;                         // f32, 16 MB
    float* V    = ws + 2 * SD;                     // f32; becomes O after transpose
    float* O    = V;
    u16*   Vth  = (u16*)(ws + 3 * SD);             // bf16-hi Vt (8 MB)
    u16*   Vtl  = Vth + SD;                        // bf16-lo Vt (8 MB)
    float* sel0 = ws + 4 * SD;                     // NH*SEQ floats
    int*   evct = (int*)(ws + 4 * SD + (size_t)NH * SEQ);
    float* Sc   = ws + 4 * SD + 2 * (size_t)NH * SEQ;   // g * SEQ*SEQ floats

    // staging (hi/lo splits) in the not-yet-used Sc region: 4 arrays x SD u16
    u16* hh = (u16*)Sc;        // hidden hi (later: O hi)
    u16* hl = hh + SD;         // hidden lo (later: O lo)
    u16* wh = hl + SD;         // current weight hi (reused per weight)
    u16* wl = wh + SD;         // current weight lo

    const size_t fixedB   = (4 * SD + 2 * (size_t)NH * SEQ) * sizeof(float);
    const size_t perHeadB = (size_t)SEQ * SEQ * sizeof(float);
    int g = NH;
    while (g > 1 && fixedB + (size_t)g * perHeadB > ws_size) g >>= 1;

    const int N4 = (int)(SD / 4);
    const int CB = (N4 + 255) / 256;

    // 0-1. split + projections (weights staged sequentially), LDS-staged GEMM
    split_kernel<<<CB, 256, 0, stream>>>(hidden, hh, hl, N4);
    split_kernel<<<CB, 256, 0, stream>>>(wq, wh, wl, N4);
    gemm_nt_staged<<<dim3(16,16), 256, 0, stream>>>(hh, hl, wh, wl, Q, 1.f);
    split_kernel<<<CB, 256, 0, stream>>>(wk, wh, wl, N4);
    gemm_nt_staged<<<dim3(16,16), 256, 0, stream>>>(hh, hl, wh, wl, K, 1.f);
    split_kernel<<<CB, 256, 0, stream>>>(wv, wh, wl, N4);
    gemm_nt_staged<<<dim3(16,16), 256, 0, stream>>>(hh, hl, wh, wl, V, 1.f);

    // 2. RoPE on Q, K (f32, in place)
    rope_qk<<<dim3(SEQ, NH / 4), 256, 0, stream>>>(Q, K, pos);

    // 3. V -> Vt hi/lo (V storage then becomes O)
    transpose_v<<<dim3(SEQ / 32, HD / 32, NH), dim3(32, 32), 0, stream>>>(V, Vth, Vtl);

    // 4-8 per head-group
    for (int h0 = 0; h0 < NH; h0 += g) {
        int gc = min(g, NH - h0);
        // QK logits: f32 Q,K split in-register, causal tiles, f32 out
        mfma_nt<true,true,true,false><<<dim3(16,16,gc), 256, 0, stream>>>(
            Q + (size_t)h0 * HD, nullptr, K + (size_t)h0 * HD, nullptr, Sc, HD,
            DIM, DIM, SEQ, HD, HD, (long)SEQ * SEQ, QK_SCALE);
        softmax_rows<<<dim3(SEQ, gc), 256, 0, stream>>>(Sc);
        warmup_select<<<dim3(SEQ / 256, gc), 256, 0, stream>>>(Sc, sel0);
        h2o_scan11<<<dim3(gc), 64, 0, stream>>>(Sc, sel0, evct);
        mask_renorm<<<dim3(SEQ - CACHEB, gc), 256, 0, stream>>>(Sc, evct);
        // PV: probs f32 split in-register (K-truncated), Vt pre-split, f32 out
        mfma_nt<true,false,false,true><<<dim3(1,16,gc), 256, 0, stream>>>(
            Sc, nullptr, Vth + (size_t)h0 * HD * SEQ, Vtl + (size_t)h0 * HD * SEQ,
            O + (size_t)h0 * HD, SEQ, SEQ, SEQ, DIM,
            (long)SEQ * SEQ, (long)HD * SEQ, HD, 1.f);
    }

    // 9. final projection via staged path: pre-split O, then out = O @ wo^T.
    split_kernel<<<CB, 256, 0, stream>>>(O, hh, hl, N4);
    split_kernel<<<CB, 256, 0, stream>>>(wo, wh, wl, N4);
    gemm_nt_staged<<<dim3(16,16), 256, 0, stream>>>(hh, hl, wh, wl, out, 1.f);
}

// Round 9
// 3046.276 us; speedup vs baseline: 1.4456x; 1.1876x over previous
//
#include <hip/hip_runtime.h>
#include <math.h>

#define SEQ 2048
#define DIM 2048
#define NH 16
#define HD 128
#define CACHEB 408
#define RECENT 204
#define PEN 0.4f
#define QK_SCALE 0.08838834764831845f  // 1/sqrt(128)
#define BIGT 0x7fffffff

typedef unsigned short u16;
typedef unsigned long long u64;
typedef __attribute__((ext_vector_type(8))) short bh8;   // 8 bf16 (4 VGPRs)
typedef __attribute__((ext_vector_type(4))) float f32x4; // MFMA acc

__device__ __forceinline__ u16 f2bf(float x) {           // RNE f32->bf16
    unsigned u = __float_as_uint(x);
    return (u16)((u + 0x7fffu + ((u >> 16) & 1u)) >> 16);
}
__device__ __forceinline__ void splitf(float x, u16& h, u16& l) {
    h = f2bf(x);
    float hf = __uint_as_float(((unsigned)h) << 16);
    l = f2bf(x - hf);
}

// ---------------- f32 -> (hi,lo) bf16 split, 4 elems/thread ---------------
__global__ __launch_bounds__(256)
void split_kernel(const float* __restrict__ src, u16* __restrict__ dh,
                  u16* __restrict__ dl, int n4)
{
    int i = blockIdx.x * 256 + threadIdx.x;
    if (i >= n4) return;
    float4 v = ((const float4*)src)[i];
    union { u16 s[4]; unsigned long long q; } oh, ol;
    splitf(v.x, oh.s[0], ol.s[0]); splitf(v.y, oh.s[1], ol.s[1]);
    splitf(v.z, oh.s[2], ol.s[2]); splitf(v.w, oh.s[3], ol.s[3]);
    ((unsigned long long*)dh)[i] = oh.q;
    ((unsigned long long*)dl)[i] = ol.q;
}

// ---------------- split-bf16 MFMA NT GEMM (direct-from-global) ------------
// Kept for QK (K=128) and PV (TRUNCA) paths.
template<bool ASPLITF32, bool BSPLITF32, bool CAUSAL, bool TRUNCA>
__global__ __launch_bounds__(256, 2)
void mfma_nt(const void* __restrict__ Ah_, const void* __restrict__ Al_,
             const void* __restrict__ Bh_, const void* __restrict__ Bl_,
             float* __restrict__ Cp, int K, int lda, int ldb, int ldc,
             long aB, long bB, long cB, float scale)
{
    int m0 = blockIdx.y * 128, n0 = blockIdx.x * 128;
    if (CAUSAL && n0 > m0 + 127) return;

    const float* Af = (const float*)Ah_ + (size_t)blockIdx.z * aB;
    const u16*   Ah = (const u16*)Ah_   + (size_t)blockIdx.z * aB;
    const u16*   Al = (const u16*)Al_   + (size_t)blockIdx.z * aB;
    const float* Bf = (const float*)Bh_ + (size_t)blockIdx.z * bB;
    const u16*   Bh = (const u16*)Bh_   + (size_t)blockIdx.z * bB;
    const u16*   Bl = (const u16*)Bl_   + (size_t)blockIdx.z * bB;
    float* C = Cp + (size_t)blockIdx.z * cB;

    int lane = threadIdx.x & 63, wave = threadIdx.x >> 6;
    int wm = m0 + (wave >> 1) * 64, wn = n0 + (wave & 1) * 64;
    int fr = lane & 15, quad = lane >> 4;
    int kq = quad * 8;

    auto loadA = [&](int mt, int k, bh8& h, bh8& l) {
        int r = wm + mt * 16 + fr;
        if (ASPLITF32) {
            const float* p = Af + (size_t)r * lda + k + kq;
            float4 x = *(const float4*)p, y = *(const float4*)(p + 4);
            u16 hh, ll;
            splitf(x.x,hh,ll); h[0]=(short)hh; l[0]=(short)ll;
            splitf(x.y,hh,ll); h[1]=(short)hh; l[1]=(short)ll;
            splitf(x.z,hh,ll); h[2]=(short)hh; l[2]=(short)ll;
            splitf(x.w,hh,ll); h[3]=(short)hh; l[3]=(short)ll;
            splitf(y.x,hh,ll); h[4]=(short)hh; l[4]=(short)ll;
            splitf(y.y,hh,ll); h[5]=(short)hh; l[5]=(short)ll;
            splitf(y.z,hh,ll); h[6]=(short)hh; l[6]=(short)ll;
            splitf(y.w,hh,ll); h[7]=(short)hh; l[7]=(short)ll;
        } else {
            h = *(const bh8*)(Ah + (size_t)r * lda + k + kq);
            l = *(const bh8*)(Al + (size_t)r * lda + k + kq);
        }
    };
    auto loadB = [&](int nt, int k, bh8& h, bh8& l) {
        int r = wn + nt * 16 + fr;
        if (BSPLITF32) {
            const float* p = Bf + (size_t)r * ldb + k + kq;
            float4 x = *(const float4*)p, y = *(const float4*)(p + 4);
            u16 hh, ll;
            splitf(x.x,hh,ll); h[0]=(short)hh; l[0]=(short)ll;
            splitf(x.y,hh,ll); h[1]=(short)hh; l[1]=(short)ll;
            splitf(x.z,hh,ll); h[2]=(short)hh; l[2]=(short)ll;
            splitf(x.w,hh,ll); h[3]=(short)hh; l[3]=(short)ll;
            splitf(y.x,hh,ll); h[4]=(short)hh; l[4]=(short)ll;
            splitf(y.y,hh,ll); h[5]=(short)hh; l[5]=(short)ll;
            splitf(y.z,hh,ll); h[6]=(short)hh; l[6]=(short)ll;
            splitf(y.w,hh,ll); h[7]=(short)hh; l[7]=(short)ll;
        } else {
            h = *(const bh8*)(Bh + (size_t)r * ldb + k + kq);
            l = *(const bh8*)(Bl + (size_t)r * ldb + k + kq);
        }
    };

    f32x4 acc[4][4] = {};
    int Keff = TRUNCA ? min(K, m0 + 128) : K;

    for (int k0 = 0; k0 < Keff; k0 += 32) {
        bh8 ah[4], al[4], bh[4], bl[4];
        #pragma unroll
        for (int i = 0; i < 4; i++) { loadA(i, k0, ah[i], al[i]); loadB(i, k0, bh[i], bl[i]); }
        #pragma unroll
        for (int mt = 0; mt < 4; mt++)
            #pragma unroll
            for (int nt = 0; nt < 4; nt++) {
                acc[mt][nt] = __builtin_amdgcn_mfma_f32_16x16x32_bf16(ah[mt], bh[nt], acc[mt][nt], 0, 0, 0);
                acc[mt][nt] = __builtin_amdgcn_mfma_f32_16x16x32_bf16(ah[mt], bl[nt], acc[mt][nt], 0, 0, 0);
                acc[mt][nt] = __builtin_amdgcn_mfma_f32_16x16x32_bf16(al[mt], bh[nt], acc[mt][nt], 0, 0, 0);
            }
    }

    #pragma unroll
    for (int mt = 0; mt < 4; mt++)
        #pragma unroll
        for (int r = 0; r < 4; r++) {
            int row = wm + mt * 16 + quad * 4 + r;
            #pragma unroll
            for (int nt = 0; nt < 4; nt++) {
                int col = wn + nt * 16 + fr;
                C[(size_t)row * ldc + col] = acc[mt][nt][r] * scale;
            }
        }
}

// ---------------- split-bf16 MFMA NT GEMM, LDS-staged (2048^3 only) -------
__global__ __launch_bounds__(256, 2)
void gemm_nt_staged(const u16* __restrict__ Ah, const u16* __restrict__ Al,
                    const u16* __restrict__ Bh, const u16* __restrict__ Bl,
                    float* __restrict__ C, float scale)
{
    __shared__ u16 sm[2][4][128 * 32];   // [buf][Ah,Al,Bh,Bl][row*32+col], 64 KB

    int m0 = blockIdx.y * 128, n0 = blockIdx.x * 128;
    int tid = threadIdx.x;
    int lane = tid & 63, wave = tid >> 6;
    int fr = lane & 15, quad = lane >> 4;
    int wmr = (wave >> 1) * 64;
    int wnr = (wave & 1) * 64;

    auto stage = [&](int buf, int k0) {
        #pragma unroll
        for (int a = 0; a < 4; a++) {
            const u16* g = (a == 0) ? Ah : (a == 1) ? Al : (a == 2) ? Bh : Bl;
            int r0 = (a < 2) ? m0 : n0;
            #pragma unroll
            for (int hf = 0; hf < 2; hf++) {
                int c = hf * 256 + wave * 64 + lane;
                const u16* src = g + (size_t)(r0 + (c >> 2)) * DIM + k0 + (c & 3) * 8;
                u16* dst = &sm[buf][a][(hf * 256 + wave * 64) * 8];
                __builtin_amdgcn_global_load_lds(
                    (const __attribute__((address_space(1))) void*)src,
                    (__attribute__((address_space(3))) void*)dst, 16, 0, 0);
            }
        }
    };

    f32x4 acc[4][4] = {};

    auto cmpt = [&](int buf) {
        bh8 ah[4], al[4], bhf[4], blf[4];
        #pragma unroll
        for (int i = 0; i < 4; i++) {
            int ra = (wmr + i * 16 + fr) * 32 + quad * 8;
            int rb = (wnr + i * 16 + fr) * 32 + quad * 8;
            ah[i]  = *(const bh8*)&sm[buf][0][ra];
            al[i]  = *(const bh8*)&sm[buf][1][ra];
            bhf[i] = *(const bh8*)&sm[buf][2][rb];
            blf[i] = *(const bh8*)&sm[buf][3][rb];
        }
        #pragma unroll
        for (int mt = 0; mt < 4; mt++)
            #pragma unroll
            for (int nt = 0; nt < 4; nt++) {
                acc[mt][nt] = __builtin_amdgcn_mfma_f32_16x16x32_bf16(ah[mt], bhf[nt], acc[mt][nt], 0, 0, 0);
                acc[mt][nt] = __builtin_amdgcn_mfma_f32_16x16x32_bf16(ah[mt], blf[nt], acc[mt][nt], 0, 0, 0);
                acc[mt][nt] = __builtin_amdgcn_mfma_f32_16x16x32_bf16(al[mt], bhf[nt], acc[mt][nt], 0, 0, 0);
            }
    };

    stage(0, 0);
    __syncthreads();
    int cur = 0;
    for (int k0 = 0; k0 < DIM; k0 += 32) {
        if (k0 + 32 < DIM) stage(cur ^ 1, k0 + 32);
        cmpt(cur);
        __syncthreads();
        cur ^= 1;
    }

    int wm = m0 + wmr, wn = n0 + wnr;
    #pragma unroll
    for (int mt = 0; mt < 4; mt++)
        #pragma unroll
        for (int r = 0; r < 4; r++) {
            int row = wm + mt * 16 + quad * 4 + r;
            #pragma unroll
            for (int nt = 0; nt < 4; nt++) {
                int col = wn + nt * 16 + fr;
                C[(size_t)row * DIM + col] = acc[mt][nt][r] * scale;
            }
        }
}

// ---------------- RoPE in place on Q and K (f32) ---------------------------
__global__ __launch_bounds__(256)
void rope_qk(float* __restrict__ Q, float* __restrict__ K, const int* __restrict__ pos_ids)
{
    int s = blockIdx.x;
    int i = threadIdx.x & 63;
    int h = blockIdx.y * 4 + (threadIdx.x >> 6);
    double p = (double)pos_ids[s];
    double invf = exp(-((double)(2 * i) / (double)HD) * 9.210340371976184); // ln(10000)
    double ang = p * invf;
    float c = (float)cos(ang), sn = (float)sin(ang);
    size_t b = (size_t)s * DIM + (size_t)h * HD;
    float q0 = Q[b + i], q1 = Q[b + i + 64];
    Q[b + i]      = q0 * c - q1 * sn;
    Q[b + i + 64] = q1 * c + q0 * sn;
    float k0 = K[b + i], k1 = K[b + i + 64];
    K[b + i]      = k0 * c - k1 * sn;
    K[b + i + 64] = k1 * c + k0 * sn;
}

// ---------------- V(f32) -> Vt hi/lo bf16 [h][hd][s] -----------------------
__global__ __launch_bounds__(1024)
void transpose_v(const float* __restrict__ V, u16* __restrict__ Vth, u16* __restrict__ Vtl)
{
    __shared__ float tile[32][33];
    int h = blockIdx.z;
    int j0 = blockIdx.x * 32, d0 = blockIdx.y * 32;
    int tx = threadIdx.x, ty = threadIdx.y;
    tile[ty][tx] = V[(size_t)(j0 + ty) * DIM + (size_t)h * HD + d0 + tx];
    __syncthreads();
    u16 hh, ll; splitf(tile[tx][ty], hh, ll);
    size_t idx = (size_t)h * HD * SEQ + (size_t)(d0 + ty) * SEQ + j0 + tx;
    Vth[idx] = hh; Vtl[idx] = ll;
}

// ---------------- row softmax (causal) in place on Sc ---------------------
__global__ __launch_bounds__(256)
void softmax_rows(float* __restrict__ Sc)
{
    int r = blockIdx.x, h = blockIdx.y;
    float* row = Sc + ((size_t)h * SEQ + r) * SEQ;
    int n = r + 1;
    __shared__ float red[256];
    int tid = threadIdx.x;
    float mx = -INFINITY;
    for (int j = tid; j < n; j += 256) mx = fmaxf(mx, row[j]);
    red[tid] = mx; __syncthreads();
    for (int s = 128; s; s >>= 1) { if (tid < s) red[tid] = fmaxf(red[tid], red[tid + s]); __syncthreads(); }
    mx = red[0]; __syncthreads();
    float sum = 0.f;
    for (int j = tid; j < n; j += 256) { float e = expf(row[j] - mx); row[j] = e; sum += e; }
    red[tid] = sum; __syncthreads();
    for (int s = 128; s; s >>= 1) { if (tid < s) red[tid] += red[tid + s]; __syncthreads(); }
    float inv = 1.f / red[0];
    for (int j = tid; j < n; j += 256) row[j] *= inv;
    for (int j = n + tid; j < SEQ; j += 256) row[j] = 0.f;
}

// ---------------- parallel warmup: select0[h][c] = sum_t PEN^(407-t)*Sc[t][c]
__global__ __launch_bounds__(256)
void warmup_select(const float* __restrict__ Sc, float* __restrict__ sel0)
{
    int h = blockIdx.y;
    int col = blockIdx.x * 256 + threadIdx.x;
    const float* S = Sc + (size_t)h * SEQ * SEQ + col;
    float s = 0.f;
    #pragma unroll 4
    for (int t = 0; t < CACHEB; t++) s = PEN * s + S[(size_t)t * SEQ];
    sel0[h * SEQ + col] = s;
}

// ---------------- DPP cross-lane helpers ----------------------------------
#define DPP_SUMSTEP(x, ctrl) \
    x += __int_as_float(__builtin_amdgcn_update_dpp(0, __float_as_int(x), ctrl, 0xF, 0xF, true))
#define DPP_SUMBC(x, ctrl) \
    x += __int_as_float(__builtin_amdgcn_update_dpp(0, __float_as_int(x), ctrl, 0xF, 0xF, false))

__device__ __forceinline__ float wave_sum64(float x) {
    DPP_SUMSTEP(x, 0x111); DPP_SUMSTEP(x, 0x112);
    DPP_SUMSTEP(x, 0x114); DPP_SUMSTEP(x, 0x118);
    DPP_SUMBC(x, 0x142);   DPP_SUMBC(x, 0x143);
    return __int_as_float(__builtin_amdgcn_readlane(__float_as_int(x), 63));
}

// 64-bit (value,pos) key min-reduction across the wave.
#define DPP_MIN_U64(x, ctrl) do { \
    unsigned lo_ = (unsigned)(x), hi_ = (unsigned)((x) >> 32); \
    unsigned nlo_ = (unsigned)__builtin_amdgcn_update_dpp((int)lo_, (int)lo_, ctrl, 0xF, 0xF, false); \
    unsigned nhi_ = (unsigned)__builtin_amdgcn_update_dpp((int)hi_, (int)hi_, ctrl, 0xF, 0xF, false); \
    u64 o_ = ((u64)nhi_ << 32) | nlo_; \
    if (o_ < (x)) (x) = o_; \
} while (0)

__device__ __forceinline__ u64 wave_min64_u64(u64 x) {
    DPP_MIN_U64(x, 0x111); DPP_MIN_U64(x, 0x112);
    DPP_MIN_U64(x, 0x114); DPP_MIN_U64(x, 0x118);
    DPP_MIN_U64(x, 0x142); DPP_MIN_U64(x, 0x143);
    unsigned rlo = (unsigned)__builtin_amdgcn_readlane((int)(unsigned)x, 63);
    unsigned rhi = (unsigned)__builtin_amdgcn_readlane((int)(unsigned)(x >> 32), 63);
    return ((u64)rhi << 32) | rlo;
}

__device__ __forceinline__ u64 umin64(u64 a, u64 b) { return a < b ? a : b; }

// ---------------- H2O scan: slot-compacted + 1-step gather cover ----------
// scan11 + latency cover: only ONE slot's position changes per step, so the
// gather for row t+1 is issued at the START of step t with pre-insert
// positions (1 full step of latency cover); the single slot evicted at step
// t is patched at step t+1 with the prefetched DIAGONAL row[t+1][t+1]
// (that slot's new position IS t+1). Sum stays in identical slot order,
// per-element ops identical, u64 argmin exact => bit-identical evictions.
__global__ __launch_bounds__(64, 1)
void h2o_scan12(const float* __restrict__ Sc, const float* __restrict__ sel0,
                int* __restrict__ evict)
{
    __shared__ int et[SEQ];               // 8 KB

    int h = blockIdx.x;
    int l = threadIdx.x;                  // 0..63, one wave
    const float* Sh = Sc + (size_t)h * SEQ * SEQ;

    #pragma unroll
    for (int s = 0; s < SEQ / 64; s++) et[s * 64 + l] = BIGT;

    // slot state (all indexing compile-time constant -> stays in VGPRs)
    unsigned pos[8]; unsigned lowb[8]; float sel[8];
    #pragma unroll
    for (int j = 0; j < 8; j++) {
        int gid = l * 8 + j;
        int p = (gid <= CACHEB) ? gid : 2047;       // real: 0..408; dummy: 2047
        pos[j]  = (unsigned)p;
        lowb[j] = ((unsigned)p << 9) | (unsigned)gid;
        sel[j]  = sel0[h * SEQ + p];                // sel0[2047] == 0
    }

    float bA[8], bB[8];
    float dgA = 0.f, dgB = 0.f;          // prefetched diagonals
    unsigned evg = 0xffffu;              // gid evicted last step (no match init)

    auto gather = [&](int t, float (&b)[8]) {
        const float* rp = Sh + (size_t)t * SEQ;
        #pragma unroll
        for (int j = 0; j < 8; j++) b[j] = rp[pos[j]];
    };
    gather(CACHEB, bA);                  // positions = initial (pre any evict)

    // step t: cur was gathered 1 step ago (pre-insert positions of step t-1);
    // patch the slot evicted at step t-1 with dgc = row_t[t]; then the
    // verbatim scan11 math. Issue gather(t+1)+diag(t+1) FIRST (positions are
    // pre-insert = after-step-(t-1), correct for all slots that survive).
    auto step = [&](int t, float (&cur)[8], float (&nxt)[8],
                    float dgc, float& dgn, bool issue) {
        if (issue) {
            const float* rp = Sh + (size_t)(t + 1) * SEQ;
            #pragma unroll
            for (int j = 0; j < 8; j++) nxt[j] = rp[pos[j]];
            dgn = rp[t + 1];             // diagonal, wave-uniform address
        }

        // patch: slot evg (evicted at t-1) now has pos t -> value = diag t
        bool pmine = (int)(evg >> 3) == l;
        #pragma unroll
        for (int j = 0; j < 8; j++)
            if (pmine && ((evg & 7u) == (unsigned)j)) cur[j] = dgc;

        float s01 = cur[0] + cur[1], s23 = cur[2] + cur[3];
        float s45 = cur[4] + cur[5], s67 = cur[6] + cur[7];
        float part = wave_sum64((s01 + s23) + (s45 + s67));
        float inv = 1.f / part;

        int tmr = t - RECENT;
        u64 k[8];
        #pragma unroll
        for (int j = 0; j < 8; j++) {
            float s2 = fmaf(cur[j], inv, sel[j] * PEN);   // identical ops
            sel[j] = s2;
            unsigned hi = __float_as_uint(s2) |
                          (unsigned)((int)(tmr - (int)pos[j]) >> 31);
            k[j] = ((u64)hi << 32) | lowb[j];
        }
        u64 m01 = umin64(k[0], k[1]), m23 = umin64(k[2], k[3]);
        u64 m45 = umin64(k[4], k[5]), m67 = umin64(k[6], k[7]);
        u64 lmin = umin64(umin64(m01, m23), umin64(m45, m67));
        u64 g = wave_min64_u64(lmin);

        unsigned lo32 = (unsigned)g;
        unsigned bpos = (lo32 >> 9) & 0x7ffu;
        unsigned gid  = lo32 & 0x1ffu;
        if (l == 0) et[bpos] = t;

        bool mine = (int)(gid >> 3) == l;
        unsigned np = (unsigned)(t + 1);
        #pragma unroll
        for (int j = 0; j < 8; j++) {
            bool hit = mine && ((gid & 7u) == (unsigned)j);
            if (hit) { pos[j] = np; lowb[j] = (np << 9) | gid; sel[j] = 0.f; }
        }
        evg = gid;
    };

    int t = CACHEB;
    for (; t + 1 <= SEQ - 2; t += 2) {
        step(t,     bA, bB, dgA, dgB, true);
        step(t + 1, bB, bA, dgB, dgA, t + 1 < SEQ - 2);
    }
    if (t <= SEQ - 2) step(t, bA, bB, dgA, dgB, false);   // t = 2046

    #pragma unroll
    for (int s = 0; s < SEQ / 64; s++)
        evict[h * SEQ + s * 64 + l] = et[s * 64 + l];
}

// ---------------- apply mask + renormalize rows >= CACHEB in place --------
__global__ __launch_bounds__(256)
void mask_renorm(float* __restrict__ Sc, const int* __restrict__ evict)
{
    int r = CACHEB + blockIdx.x;
    int h = blockIdx.y;
    float* row = Sc + ((size_t)h * SEQ + r) * SEQ;
    const int* et = evict + h * SEQ;
    int tid = threadIdx.x;
    __shared__ float red[256];
    float v[8]; float sum = 0.f;
    #pragma unroll
    for (int s = 0; s < 8; s++) {
        int c = s * 256 + tid;
        float x = row[c];
        v[s] = (et[c] >= r) ? x : 0.f;
        sum += v[s];
    }
    red[tid] = sum; __syncthreads();
    for (int s = 128; s; s >>= 1) { if (tid < s) red[tid] += red[tid + s]; __syncthreads(); }
    float inv = 1.f / red[0];
    #pragma unroll
    for (int s = 0; s < 8; s++) row[s * 256 + tid] = v[s] * inv;
}

extern "C" void kernel_launch(void* const* d_in, const int* in_sizes, int n_in,
                              void* d_out, int out_size, void* d_ws, size_t ws_size,
                              hipStream_t stream)
{
    const float* hidden = (const float*)d_in[0];
    const int*   pos    = (const int*)d_in[2];
    const float* wq     = (const float*)d_in[3];
    const float* wk     = (const float*)d_in[4];
    const float* wv     = (const float*)d_in[5];
    const float* wo     = (const float*)d_in[6];
    float* out = (float*)d_out;

    float* ws = (float*)d_ws;
    const size_t SD = (size_t)SEQ * DIM;           // 4M elems
    float* Q    = ws;                              // f32, 16 MB
    float* K    = ws + SD;                         // f32, 16 MB
    float* V    = ws + 2 * SD;                     // f32; becomes O after transpose
    float* O    = V;
    u16*   Vth  = (u16*)(ws + 3 * SD);             // bf16-hi Vt (8 MB)
    u16*   Vtl  = Vth + SD;                        // bf16-lo Vt (8 MB)
    float* sel0 = ws + 4 * SD;                     // NH*SEQ floats
    int*   evct = (int*)(ws + 4 * SD + (size_t)NH * SEQ);
    float* Sc   = ws + 4 * SD + 2 * (size_t)NH * SEQ;   // g * SEQ*SEQ floats

    // staging (hi/lo splits) in the not-yet-used Sc region: 4 arrays x SD u16
    u16* hh = (u16*)Sc;        // hidden hi (later: O hi)
    u16* hl = hh + SD;         // hidden lo (later: O lo)
    u16* wh = hl + SD;         // current weight hi (reused per weight)
    u16* wl = wh + SD;         // current weight lo

    const size_t fixedB   = (4 * SD + 2 * (size_t)NH * SEQ) * sizeof(float);
    const size_t perHeadB = (size_t)SEQ * SEQ * sizeof(float);
    int g = NH;
    while (g > 1 && fixedB + (size_t)g * perHeadB > ws_size) g >>= 1;

    const int N4 = (int)(SD / 4);
    const int CB = (N4 + 255) / 256;

    // 0-1. split + projections (weights staged sequentially), LDS-staged GEMM
    split_kernel<<<CB, 256, 0, stream>>>(hidden, hh, hl, N4);
    split_kernel<<<CB, 256, 0, stream>>>(wq, wh, wl, N4);
    gemm_nt_staged<<<dim3(16,16), 256, 0, stream>>>(hh, hl, wh, wl, Q, 1.f);
    split_kernel<<<CB, 256, 0, stream>>>(wk, wh, wl, N4);
    gemm_nt_staged<<<dim3(16,16), 256, 0, stream>>>(hh, hl, wh, wl, K, 1.f);
    split_kernel<<<CB, 256, 0, stream>>>(wv, wh, wl, N4);
    gemm_nt_staged<<<dim3(16,16), 256, 0, stream>>>(hh, hl, wh, wl, V, 1.f);

    // 2. RoPE on Q, K (f32, in place)
    rope_qk<<<dim3(SEQ, NH / 4), 256, 0, stream>>>(Q, K, pos);

    // 3. V -> Vt hi/lo (V storage then becomes O)
    transpose_v<<<dim3(SEQ / 32, HD / 32, NH), dim3(32, 32), 0, stream>>>(V, Vth, Vtl);

    // 4-8 per head-group
    for (int h0 = 0; h0 < NH; h0 += g) {
        int gc = min(g, NH - h0);
        // QK logits: f32 Q,K split in-register, causal tiles, f32 out
        mfma_nt<true,true,true,false><<<dim3(16,16,gc), 256, 0, stream>>>(
            Q + (size_t)h0 * HD, nullptr, K + (size_t)h0 * HD, nullptr, Sc, HD,
            DIM, DIM, SEQ, HD, HD, (long)SEQ * SEQ, QK_SCALE);
        softmax_rows<<<dim3(SEQ, gc), 256, 0, stream>>>(Sc);
        warmup_select<<<dim3(SEQ / 256, gc), 256, 0, stream>>>(Sc, sel0);
        h2o_scan12<<<dim3(gc), 64, 0, stream>>>(Sc, sel0, evct);
        mask_renorm<<<dim3(SEQ - CACHEB, gc), 256, 0, stream>>>(Sc, evct);
        // PV: probs f32 split in-register (K-truncated), Vt pre-split, f32 out
        mfma_nt<true,false,false,true><<<dim3(1,16,gc), 256, 0, stream>>>(
            Sc, nullptr, Vth + (size_t)h0 * HD * SEQ, Vtl + (size_t)h0 * HD * SEQ,
            O + (size_t)h0 * HD, SEQ, SEQ, SEQ, DIM,
            (long)SEQ * SEQ, (long)HD * SEQ, HD, 1.f);
    }

    // 9. final projection via staged path: pre-split O, then out = O @ wo^T.
    split_kernel<<<CB, 256, 0, stream>>>(O, hh, hl, N4);
    split_kernel<<<CB, 256, 0, stream>>>(wo, wh, wl, N4);
    gemm_nt_staged<<<dim3(16,16), 256, 0, stream>>>(hh, hl, wh, wl, out, 1.f);
}